// Round 13
// baseline (517.164 us; speedup 1.0000x reference)
//
#include <hip/hip_runtime.h>
#include <hip/hip_bf16.h>
#include <cstdint>
#include <cstddef>

// ---------------------------------------------------------------------------
// SelfAttention (B=2, S=4096, H=2048, fp32 in/out), fp16 MFMA internally.
// Round 13: READ-AHEAD schedule — phase p issues the ds_reads for phase
// p+1's MFMA, so reads execute in the LDS pipe UNDER the current MFMA
// (the 42% plateau = serial reads->MFMA; model: 768cyc reads + 621cyc MFMA
// per K-tile per CU). Register budget: afA+afB+b0+b1 = 96 + acc 128 ≈ 245
// (round 11 spilled at 5 sets). Raw s_barrier does NOT drain lgkm; C++
// reads let the compiler insert counted waits; SCHED0 pins read-issue
// above the MFMA cluster.
//   read slots: ph1{b0,b1(buf)} ph2{afB(buf)} ph3{} ph4{afA(buf^1)}
//   stages (= round 8, verified): ph1/ph2 buf1.A0/A1(t+1), ph3/ph4
//   buf0.B0/B1(t+2), ph5/ph6 buf0.A0/A1(t+2), ph7/ph8 buf1.B0/B1(t+3)
//   VMC(2) moved BEFORE ph3/ph7 closing barrier (FIFO: 10 outstanding,
//   drain 8 = all of next tile) so ph4/ph8 may read the other buffer.
// fp16 scores retained (round 10, verified).
// ---------------------------------------------------------------------------

typedef _Float16 half8 __attribute__((ext_vector_type(8)));
typedef _Float16 half4 __attribute__((ext_vector_type(4)));
typedef float    f32x4 __attribute__((ext_vector_type(4)));

__device__ __forceinline__ void gld_lds16(const void* g, void* l) {
  __builtin_amdgcn_global_load_lds(
      (const __attribute__((address_space(1))) unsigned int*)g,
      (__attribute__((address_space(3))) unsigned int*)l, 16, 0, 0);
}

#define FENCE()  asm volatile("" ::: "memory")
#define VMC(n)   asm volatile("s_waitcnt vmcnt(" #n ")" ::: "memory")
#define SBAR()   do { __builtin_amdgcn_s_barrier(); FENCE(); } while (0)
#define SCHED0() __builtin_amdgcn_sched_barrier(0)
#define PRIO1()  __builtin_amdgcn_s_setprio(1)
#define PRIO0()  __builtin_amdgcn_s_setprio(0)

// A subtile (m-half MH) from buffer RB: 8 x ds_read_b128 (C++ reads)
#define LOAD_A(dst, RB, MH) do {                                            \
  const char* _p = ldsA + ((RB)*2 + wr) * 16384 + fr * 128;                 \
  _Pragma("unroll") for (int mi = 0; mi < 4; ++mi) {                        \
    dst[mi][0] = *(const half8*)(_p + ((MH)*4 + mi) * 2048 + cS0);          \
    dst[mi][1] = *(const half8*)(_p + ((MH)*4 + mi) * 2048 + cS1);          \
  }                                                                         \
} while (0)

// B subtile (n-half NH) from buffer RB: 4 x ds_read_b128
#define LOAD_B(dst, RB, NH) do {                                            \
  const char* _p = ldsB + ((RB)*2 + (wc >> 1)) * 16384 +                    \
                   ((wc & 1) * 64 + fr) * 128;                              \
  _Pragma("unroll") for (int ni = 0; ni < 2; ++ni) {                        \
    dst[ni][0] = *(const half8*)(_p + ((NH)*2 + ni) * 2048 + cS0);          \
    dst[ni][1] = *(const half8*)(_p + ((NH)*2 + ni) * 2048 + cS1);          \
  }                                                                         \
} while (0)

// one C-quadrant x K=64: 16 MFMA
#define MFMA_Q(AF, BF, MH, NH)                                              \
  _Pragma("unroll") for (int mi = 0; mi < 4; ++mi)                          \
  _Pragma("unroll") for (int ni = 0; ni < 2; ++ni) {                        \
    f32x4& _c = acc[(MH)*4 + mi][(NH)*2 + ni];                              \
    _c = __builtin_amdgcn_mfma_f32_16x16x32_f16(AF[mi][0], BF[ni][0], _c, 0, 0, 0); \
    _c = __builtin_amdgcn_mfma_f32_16x16x32_f16(AF[mi][1], BF[ni][1], _c, 0, 0, 0); \
  }

// stage one 128x64 half-tile (16KB): 2 x global_load_lds(16B) per wave.
#define STAGE_A(bsel, h, kof)                                               \
  {                                                                         \
    const _Float16* _s = Abase + (size_t)((h) * 128) * lda + (kof);         \
    char* _d = ldsA + ((bsel)*2 + (h)) * 16384 + wvd;                       \
    gld_lds16(_s, _d);                                                      \
    gld_lds16(_s + lda8, _d + 1024);                                        \
  }
#define STAGE_B(bsel, h, kof)                                               \
  {                                                                         \
    const _Float16* _s = Bbase + (size_t)((h) * 128) * ldb + (kof);         \
    char* _d = ldsB + ((bsel)*2 + (h)) * 16384 + wvd;                       \
    gld_lds16(_s, _d);                                                      \
    gld_lds16(_s + ldb8, _d + 1024);                                        \
  }

// MODE 0: fp32 row-major, no bias      (final out)
// MODE 1: fp16 row-major + bias        (Q, K projections)
// MODE 2: fp16 TRANSPOSED + bias       (V -> Vt[col*ldo + row])
// MODE 3: fp16 row-major, no bias      (scores S)
template <int MODE>
__global__ __launch_bounds__(512, 2) void gemm256(
    const _Float16* __restrict__ A, int lda,
    const _Float16* __restrict__ B, int ldb,
    const float* __restrict__ bias,
    void* __restrict__ out, int ldo, int K,
    size_t sA, size_t sB, size_t sO)
{
  __shared__ __attribute__((aligned(128))) char lds[131072];
  char* ldsA = (char*)lds;       // region: (bsel*2+half)*16384
  char* ldsB = (char*)lds + 65536;

  const int tid  = threadIdx.x;
  const int wv   = tid >> 6;
  const int lane = tid & 63;
  const int wr = wv >> 2;           // wave row (M half, 128 rows)
  const int wc = wv & 3;            // wave col (64 cols)
  const int bm = blockIdx.x * 256;
  const int bn = blockIdx.y * 256;
  A += (size_t)blockIdx.z * sA;
  B += (size_t)blockIdx.z * sB;

  // fragment-read indexing (swizzle verified rounds 2-12)
  const int fr = lane & 15;
  const int kq = lane >> 4;
  const int sx = (fr & 7) << 4;
  const int cS0 = (kq * 16) ^ sx;
  const int cS1 = (64 + kq * 16) ^ sx;
  // staging indexing (verified rounds 2-12)
  const int lr  = lane >> 3;
  const int sc8 = ((lane & 7) ^ (lr & 7)) << 3;

  const _Float16* Abase = A + (size_t)(bm + wv * 16 + lr) * lda + sc8;
  const _Float16* Bbase = B + (size_t)(bn + wv * 16 + lr) * ldb + sc8;
  const size_t lda8 = (size_t)lda * 8, ldb8 = (size_t)ldb * 8;
  const int wvd = wv * 2048;

  f32x4 acc[8][4];
  const f32x4 zf = {0.f, 0.f, 0.f, 0.f};
#pragma unroll
  for (int mi = 0; mi < 8; ++mi)
#pragma unroll
    for (int ni = 0; ni < 4; ++ni) acc[mi][ni] = zf;

  half8 afA[4][2], afB[4][2], b0[2][2], b1[2][2];

  const int NT = K >> 6;        // 32 or 64 (even, >= 4)
  const int NI = NT >> 1;

  // prologue: t0 full (8 ops) + t1.{B0,B1} (4 ops); VMC(4) drains t0.
  STAGE_A(0, 0, 0); STAGE_A(0, 1, 0); STAGE_B(0, 0, 0); STAGE_B(0, 1, 0);
  STAGE_B(1, 0, 64); STAGE_B(1, 1, 64);
  VMC(4);
  SBAR();
  LOAD_A(afA, 0, 0);            // buf0.A0(t0) for ph1/ph2 MFMA
  SCHED0();

  for (int it = 0; it < NI; ++it) {
    const bool more = (it < NI - 1);
    const size_t t1k = (size_t)(2 * it + 1) * 64;
    const size_t t2k = t1k + 64;
    const size_t t3k = t1k + 128;

    // ===== group 1: tile 2it, buf0 =====
    // ph1: reads b0,b1 (buf0.B); stage buf1.A0(t+1)
    LOAD_B(b0, 0, 0); LOAD_B(b1, 0, 1);
    STAGE_A(1, 0, t1k);
    SBAR(); SCHED0();
    PRIO1(); MFMA_Q(afA, b0, 0, 0); PRIO0();
    SBAR();
    // ph2: reads afB (buf0.A mh1); stage buf1.A1(t+1)
    LOAD_A(afB, 0, 1);
    STAGE_A(1, 1, t1k);
    SBAR(); SCHED0();
    PRIO1(); MFMA_Q(afA, b1, 0, 1); PRIO0();
    SBAR();
    // ph3: no reads; stage buf0.B0(t+2); VMC before closing bar drains t+1
    if (more) STAGE_B(0, 0, t2k);
    SBAR(); SCHED0();
    PRIO1(); MFMA_Q(afB, b1, 1, 1); PRIO0();
    if (more) { VMC(2); } else { VMC(0); }
    SBAR();
    // ph4: reads afA (buf1.A mh0, tile t+1 — fenced above); stage buf0.B1(t+2)
    LOAD_A(afA, 1, 0);
    if (more) STAGE_B(0, 1, t2k);
    SBAR(); SCHED0();
    PRIO1(); MFMA_Q(afB, b0, 1, 0); PRIO0();
    SBAR();

    // ===== group 2: tile 2it+1, buf1 =====
    // ph5: reads b0,b1 (buf1.B); stage buf0.A0(t+2)
    LOAD_B(b0, 1, 0); LOAD_B(b1, 1, 1);
    if (more) STAGE_A(0, 0, t2k);
    SBAR(); SCHED0();
    PRIO1(); MFMA_Q(afA, b0, 0, 0); PRIO0();
    SBAR();
    // ph6: reads afB (buf1.A mh1); stage buf0.A1(t+2)
    LOAD_A(afB, 1, 1);
    if (more) STAGE_A(0, 1, t2k);
    SBAR(); SCHED0();
    PRIO1(); MFMA_Q(afA, b1, 0, 1); PRIO0();
    SBAR();
    // ph7: no reads; stage buf1.B0(t+3); VMC before closing bar drains t+2
    if (more) STAGE_B(1, 0, t3k);
    SBAR(); SCHED0();
    PRIO1(); MFMA_Q(afB, b1, 1, 1); PRIO0();
    if (more) { VMC(2); } else { VMC(0); }
    SBAR();
    // ph8: reads afA (buf0.A mh0, tile t+2 — fenced above); stage buf1.B1(t+3)
    if (more) { LOAD_A(afA, 0, 0); STAGE_B(1, 1, t3k); }
    SBAR(); SCHED0();
    PRIO1(); MFMA_Q(afB, b0, 1, 0); PRIO0();
    SBAR();
  }

  // epilogue. C/D frag: col = lane&15, rows = (lane>>4)*4 + j
#pragma unroll
  for (int mi = 0; mi < 8; ++mi) {
#pragma unroll
    for (int ni = 0; ni < 4; ++ni) {
      const int col  = bn + wc * 64 + ni * 16 + fr;
      const int row0 = bm + wr * 128 + mi * 16 + kq * 4;
      const f32x4 a = acc[mi][ni];
      if constexpr (MODE == 0) {
        float* O = (float*)out + (size_t)blockIdx.z * sO;
#pragma unroll
        for (int j = 0; j < 4; ++j) O[(size_t)(row0 + j) * ldo + col] = a[j];
      } else if constexpr (MODE == 1) {
        _Float16* O = (_Float16*)out;
        const float bb = bias[col];
#pragma unroll
        for (int j = 0; j < 4; ++j)
          O[(size_t)(row0 + j) * ldo + col] = (_Float16)(a[j] + bb);
      } else if constexpr (MODE == 2) {
        _Float16* O = (_Float16*)out;
        const float bb = bias[col];
        half4 h;
#pragma unroll
        for (int j = 0; j < 4; ++j) h[j] = (_Float16)(a[j] + bb);
        *(half4*)(O + (size_t)col * ldo + row0) = h;
      } else {  // MODE 3: fp16 row-major, no bias (scores)
        _Float16* O = (_Float16*)out + (size_t)blockIdx.z * sO;
#pragma unroll
        for (int j = 0; j < 4; ++j)
          O[(size_t)(row0 + j) * ldo + col] = (_Float16)a[j];
      }
    }
  }
}

__device__ __forceinline__ float wave_max_f(float v) {
#pragma unroll
  for (int o = 32; o; o >>= 1) v = fmaxf(v, __shfl_xor(v, o));
  return v;
}
__device__ __forceinline__ float wave_sum_f(float v) {
#pragma unroll
  for (int o = 32; o; o >>= 1) v += __shfl_xor(v, o);
  return v;
}

// one 256-thread block per row of 4096 fp16 scores -> fp16 probabilities
__global__ __launch_bounds__(256) void softmax_rows(
    const _Float16* __restrict__ S, _Float16* __restrict__ P)
{
  __shared__ float rmax[4], rsum[4];
  const int tid = threadIdx.x;
  const _Float16* s = S + (size_t)blockIdx.x * 4096;
  _Float16*       p = P + (size_t)blockIdx.x * 4096;

  const half8 v0 = ((const half8*)s)[tid];
  const half8 v1 = ((const half8*)s)[tid + 256];
  float f[16];
#pragma unroll
  for (int j = 0; j < 8; ++j) { f[j] = (float)v0[j]; f[8 + j] = (float)v1[j]; }

  float m = f[0];
#pragma unroll
  for (int j = 1; j < 16; ++j) m = fmaxf(m, f[j]);
  m = wave_max_f(m);
  if ((tid & 63) == 0) rmax[tid >> 6] = m;
  __syncthreads();
  m = fmaxf(fmaxf(rmax[0], rmax[1]), fmaxf(rmax[2], rmax[3]));

  float sum = 0.f;
#pragma unroll
  for (int j = 0; j < 16; ++j) { f[j] = __expf(f[j] - m); sum += f[j]; }
  sum = wave_sum_f(sum);
  if ((tid & 63) == 0) rsum[tid >> 6] = sum;
  __syncthreads();
  sum = rsum[0] + rsum[1] + rsum[2] + rsum[3];
  const float inv = 1.0f / sum;

  half8 o0, o1;
#pragma unroll
  for (int j = 0; j < 8; ++j) {
    o0[j] = (_Float16)(f[j] * inv);
    o1[j] = (_Float16)(f[8 + j] * inv);
  }
  ((half8*)p)[tid] = o0;
  ((half8*)p)[tid + 256] = o1;
}

__global__ __launch_bounds__(256) void cvt_f32_f16(
    const float* __restrict__ in, _Float16* __restrict__ out, int n4)
{
  const int stride = gridDim.x * 256;
  for (int idx = blockIdx.x * 256 + threadIdx.x; idx < n4; idx += stride) {
    const f32x4 x = ((const f32x4*)in)[idx];
    half4 h;
#pragma unroll
    for (int j = 0; j < 4; ++j) h[j] = (_Float16)x[j];
    ((half4*)out)[idx] = h;
  }
}

extern "C" void kernel_launch(void* const* d_in, const int* in_sizes, int n_in,
                              void* d_out, int out_size, void* d_ws, size_t ws_size,
                              hipStream_t stream)
{
  const float* X  = (const float*)d_in[0];
  const float* Wq = (const float*)d_in[1];
  const float* bq = (const float*)d_in[2];
  const float* Wk = (const float*)d_in[3];
  const float* bk = (const float*)d_in[4];
  const float* Wv = (const float*)d_in[5];
  const float* bv = (const float*)d_in[6];
  float* out = (float*)d_out;

  const size_t NX = (size_t)2 * 4096 * 2048;  // 16,777,216
  const size_t NW = (size_t)2048 * 2048;      //  4,194,304
  const size_t NS = (size_t)2 * 4096 * 4096;  // 33,554,432

  // Workspace layout (lifetime-aliased):
  //  [0 ..)         : Ssc fp16 (67MB) — earlier hosts Xh + W*h fp16
  //  [NS*4 ..)      : Q | Kp fp16 — later aliased by P fp16
  //  [NS*4+2*NX*2..): Vt fp16 [2048][8192]
  char* w = (char*)d_ws;
  _Float16* Ssc = (_Float16*)w;
  _Float16* Xh  = (_Float16*)w;
  _Float16* Wqh = (_Float16*)(w + NX * 2);
  _Float16* Wkh = (_Float16*)(w + NX * 2 + NW * 2);
  _Float16* Wvh = (_Float16*)(w + NX * 2 + 2 * NW * 2);
  _Float16* Q   = (_Float16*)(w + NS * 4);
  _Float16* Kp  = (_Float16*)(w + NS * 4 + NX * 2);
  _Float16* P   = (_Float16*)(w + NS * 4);            // aliases Q+Kp
  _Float16* Vt  = (_Float16*)(w + NS * 4 + 2 * NX * 2);

  // 1) fp32 -> fp16 conversions
  cvt_f32_f16<<<2048, 256, 0, stream>>>(X,  Xh,  (int)(NX / 4));
  cvt_f32_f16<<<512,  256, 0, stream>>>(Wq, Wqh, (int)(NW / 4));
  cvt_f32_f16<<<512,  256, 0, stream>>>(Wk, Wkh, (int)(NW / 4));
  cvt_f32_f16<<<512,  256, 0, stream>>>(Wv, Wvh, (int)(NW / 4));

  const dim3 blk(512);
  // 2) projections: [8192,2048] = Xh @ W^T + b
  gemm256<1><<<dim3(32, 8, 1), blk, 0, stream>>>(Xh, 2048, Wqh, 2048, bq,
                                                 Q, 2048, 2048, 0, 0, 0);
  gemm256<1><<<dim3(32, 8, 1), blk, 0, stream>>>(Xh, 2048, Wkh, 2048, bk,
                                                 Kp, 2048, 2048, 0, 0, 0);
  gemm256<2><<<dim3(32, 8, 1), blk, 0, stream>>>(Xh, 2048, Wvh, 2048, bv,
                                                 Vt, 8192, 2048, 0, 0, 0);
  // 3) scores: per batch, S = Q K^T (fp16 out)
  gemm256<3><<<dim3(16, 16, 2), blk, 0, stream>>>(
      Q, 2048, Kp, 2048, nullptr, Ssc, 4096, 2048,
      (size_t)4096 * 2048, (size_t)4096 * 2048, (size_t)4096 * 4096);
  // 4) row softmax (fp16 in) -> fp16 probs
  softmax_rows<<<8192, 256, 0, stream>>>(Ssc, P);
  // 5) out: per batch, [4096,2048] = P @ Vt^T
  gemm256<0><<<dim3(16, 8, 2), blk, 0, stream>>>(
      P, 4096, Vt, 8192, nullptr, out, 2048, 4096,
      (size_t)4096 * 4096, (size_t)4096, (size_t)4096 * 2048);
}

// Round 14
// 477.545 us; speedup vs baseline: 1.0830x; 1.0830x over previous
//
#include <hip/hip_runtime.h>
#include <hip/hip_bf16.h>
#include <cstdint>
#include <cstddef>

// ---------------------------------------------------------------------------
// SelfAttention (B=2, S=4096, H=2048, fp32 in/out), fp16 MFMA internally.
// Round 14: round-10 K-loop byte-identical (best verified, 489.8us).
// Launch-level trims only:
//  (1) ONE merged QKV projection dispatch (grid 32x24): B = contiguous
//      [6144][2048] Wq|Wk|Wv concat (already adjacent in ws); epilogue picks
//      segment by blockIdx.y>>3 (Q/K row-major +bias, V transposed +bias).
//  (2) ONE fused cvt kernel over contiguous Xh|Wqh|Wkh|Wvh destination.
// fp16 scores retained (round 10, verified).
// ---------------------------------------------------------------------------

typedef _Float16 half8 __attribute__((ext_vector_type(8)));
typedef _Float16 half4 __attribute__((ext_vector_type(4)));
typedef float    f32x4 __attribute__((ext_vector_type(4)));

__device__ __forceinline__ void gld_lds16(const void* g, void* l) {
  __builtin_amdgcn_global_load_lds(
      (const __attribute__((address_space(1))) unsigned int*)g,
      (__attribute__((address_space(3))) unsigned int*)l, 16, 0, 0);
}

#define FENCE()  asm volatile("" ::: "memory")
#define LGKM(n)  asm volatile("s_waitcnt lgkmcnt(" #n ")" ::: "memory")
#define VMC(n)   asm volatile("s_waitcnt vmcnt(" #n ")" ::: "memory")
#define SBAR()   do { __builtin_amdgcn_s_barrier(); FENCE(); } while (0)
#define SCHED0() __builtin_amdgcn_sched_barrier(0)
#define PRIO1()  __builtin_amdgcn_s_setprio(1)
#define PRIO0()  __builtin_amdgcn_s_setprio(0)

// A subtile (m-half MH) from buffer RB into af: 8 x ds_read_b128 (C++ reads)
#define LOAD_A(dst, RB, MH) do {                                            \
  const char* _p = ldsA + ((RB)*2 + wr) * 16384 + fr * 128;                 \
  _Pragma("unroll") for (int mi = 0; mi < 4; ++mi) {                        \
    dst[mi][0] = *(const half8*)(_p + ((MH)*4 + mi) * 2048 + cS0);          \
    dst[mi][1] = *(const half8*)(_p + ((MH)*4 + mi) * 2048 + cS1);          \
  }                                                                         \
} while (0)

// B subtile (n-half NH) from buffer RB into dst: 4 x ds_read_b128
#define LOAD_B(dst, RB, NH) do {                                            \
  const char* _p = ldsB + ((RB)*2 + (wc >> 1)) * 16384 +                    \
                   ((wc & 1) * 64 + fr) * 128;                              \
  _Pragma("unroll") for (int ni = 0; ni < 2; ++ni) {                        \
    dst[ni][0] = *(const half8*)(_p + ((NH)*2 + ni) * 2048 + cS0);          \
    dst[ni][1] = *(const half8*)(_p + ((NH)*2 + ni) * 2048 + cS1);          \
  }                                                                         \
} while (0)

// one C-quadrant x K=64: 16 MFMA
#define MFMA_Q(AF, BF, MH, NH)                                              \
  _Pragma("unroll") for (int mi = 0; mi < 4; ++mi)                          \
  _Pragma("unroll") for (int ni = 0; ni < 2; ++ni) {                        \
    f32x4& _c = acc[(MH)*4 + mi][(NH)*2 + ni];                              \
    _c = __builtin_amdgcn_mfma_f32_16x16x32_f16(AF[mi][0], BF[ni][0], _c, 0, 0, 0); \
    _c = __builtin_amdgcn_mfma_f32_16x16x32_f16(AF[mi][1], BF[ni][1], _c, 0, 0, 0); \
  }

// stage one 128x64 half-tile (16KB): 2 x global_load_lds(16B) per wave.
// LDS linear; global source column pre-swizzled (involution, both-sides).
#define STAGE_A(bsel, h, kof)                                               \
  {                                                                         \
    const _Float16* _s = Abase + (size_t)((h) * 128) * lda + (kof);         \
    char* _d = ldsA + ((bsel)*2 + (h)) * 16384 + wvd;                       \
    gld_lds16(_s, _d);                                                      \
    gld_lds16(_s + lda8, _d + 1024);                                        \
  }
#define STAGE_B(bsel, h, kof)                                               \
  {                                                                         \
    const _Float16* _s = Bbase + (size_t)((h) * 128) * ldb + (kof);         \
    char* _d = ldsB + ((bsel)*2 + (h)) * 16384 + wvd;                       \
    gld_lds16(_s, _d);                                                      \
    gld_lds16(_s + ldb8, _d + 1024);                                        \
  }

// MODE 0: fp32 row-major, no bias                    (final out)
// MODE 1: merged QKV projection — seg = blockIdx.y>>3:
//         seg0: Q fp16 row-major +bq | seg1: K fp16 row-major +bk |
//         seg2: V fp16 TRANSPOSED +bv (Vt[col*8192 + row])
// MODE 3: fp16 row-major, no bias                    (scores S)
template <int MODE>
__global__ __launch_bounds__(512) void gemm256(
    const _Float16* __restrict__ A, int lda,
    const _Float16* __restrict__ B, int ldb,
    const float* __restrict__ bias, const float* __restrict__ bias2,
    const float* __restrict__ bias3,
    void* __restrict__ out, void* __restrict__ out2, void* __restrict__ out3,
    int ldo, int K, size_t sA, size_t sB, size_t sO)
{
  __shared__ __attribute__((aligned(128))) char lds[131072];
  char* ldsA = (char*)lds;       // region: (bsel*2+half)*16384
  char* ldsB = (char*)lds + 65536;

  const int tid  = threadIdx.x;
  const int wv   = tid >> 6;
  const int lane = tid & 63;
  const int wr = wv >> 2;           // wave row (M half, 128 rows)
  const int wc = wv & 3;            // wave col (64 cols)
  const int bm = blockIdx.x * 256;
  const int bn = blockIdx.y * 256;
  A += (size_t)blockIdx.z * sA;
  B += (size_t)blockIdx.z * sB;

  // fragment-read indexing (swizzle verified rounds 2-13)
  const int fr = lane & 15;
  const int kq = lane >> 4;
  const int sx = (fr & 7) << 4;
  const int cS0 = (kq * 16) ^ sx;
  const int cS1 = (64 + kq * 16) ^ sx;
  // staging indexing (verified rounds 2-13)
  const int lr  = lane >> 3;
  const int sc8 = ((lane & 7) ^ (lr & 7)) << 3;

  const _Float16* Abase = A + (size_t)(bm + wv * 16 + lr) * lda + sc8;
  const _Float16* Bbase = B + (size_t)(bn + wv * 16 + lr) * ldb + sc8;
  const size_t lda8 = (size_t)lda * 8, ldb8 = (size_t)ldb * 8;
  const int wvd = wv * 2048;

  f32x4 acc[8][4];
  const f32x4 zf = {0.f, 0.f, 0.f, 0.f};
#pragma unroll
  for (int mi = 0; mi < 8; ++mi)
#pragma unroll
    for (int ni = 0; ni < 4; ++ni) acc[mi][ni] = zf;

  half8 af[4][2], bf0[2][2], bf1[2][2];

  const int NT = K >> 6;        // 32 or 64 (even, >= 4)
  const int NI = NT >> 1;

  // prologue: t0 full (8 loads) + t1.{B0,B1} (4 loads); VMC(4) drains t0.
  STAGE_A(0, 0, 0); STAGE_A(0, 1, 0); STAGE_B(0, 0, 0); STAGE_B(0, 1, 0);
  STAGE_B(1, 0, 64); STAGE_B(1, 1, 64);
  VMC(4);
  SBAR();

  for (int it = 0; it < NI; ++it) {
    const bool more = (it < NI - 1);
    const size_t t1k = (size_t)(2 * it + 1) * 64;   // buf1 tile (this group)
    const size_t t2k = t1k + 64;                    // buf0 next tile
    const size_t t3k = t1k + 128;                   // buf1 next tile

    // ===== group 1: buf0, tile 2it =====
    LOAD_A(af, 0, 0); LOAD_B(bf0, 0, 0);
    STAGE_A(1, 0, t1k);
    LGKM(8);
    SBAR(); LGKM(0); SCHED0();
    PRIO1(); MFMA_Q(af, bf0, 0, 0); PRIO0();
    SBAR();
    LOAD_B(bf1, 0, 1);
    STAGE_A(1, 1, t1k);
    SBAR(); LGKM(0); SCHED0();
    PRIO1(); MFMA_Q(af, bf1, 0, 1); PRIO0();
    SBAR();
    LOAD_A(af, 0, 1);
    if (more) STAGE_B(0, 0, t2k);
    SBAR(); LGKM(0); SCHED0();
    PRIO1(); MFMA_Q(af, bf1, 1, 1); PRIO0();
    SBAR();
    if (more) STAGE_B(0, 1, t2k);
    SBAR(); SCHED0();
    PRIO1(); MFMA_Q(af, bf0, 1, 0); PRIO0();
    if (more) { VMC(4); } else { VMC(0); }
    SBAR();

    // ===== group 2: buf1, tile 2it+1 =====
    LOAD_A(af, 1, 0); LOAD_B(bf0, 1, 0);
    if (more) STAGE_A(0, 0, t2k);
    LGKM(8);
    SBAR(); LGKM(0); SCHED0();
    PRIO1(); MFMA_Q(af, bf0, 0, 0); PRIO0();
    SBAR();
    LOAD_B(bf1, 1, 1);
    if (more) STAGE_A(0, 1, t2k);
    SBAR(); LGKM(0); SCHED0();
    PRIO1(); MFMA_Q(af, bf1, 0, 1); PRIO0();
    SBAR();
    LOAD_A(af, 1, 1);
    if (more) STAGE_B(1, 0, t3k);
    SBAR(); LGKM(0); SCHED0();
    PRIO1(); MFMA_Q(af, bf1, 1, 1); PRIO0();
    SBAR();
    if (more) STAGE_B(1, 1, t3k);
    SBAR(); SCHED0();
    PRIO1(); MFMA_Q(af, bf0, 1, 0); PRIO0();
    if (more) { VMC(4); } else { VMC(0); }
    SBAR();
  }

  // epilogue. C/D frag: col = lane&15, rows = (lane>>4)*4 + j
  if constexpr (MODE == 1) {
    const int seg = blockIdx.y >> 3;          // 0=Q, 1=K, 2=V
    const int cb  = (blockIdx.y & 7) * 256;   // segment-local col base
    _Float16* O; const float* bp;
    if (seg == 0)      { O = (_Float16*)out;  bp = bias;  }
    else if (seg == 1) { O = (_Float16*)out2; bp = bias2; }
    else               { O = (_Float16*)out3; bp = bias3; }
#pragma unroll
    for (int mi = 0; mi < 8; ++mi) {
#pragma unroll
      for (int ni = 0; ni < 4; ++ni) {
        const int colL = cb + wc * 64 + ni * 16 + fr;
        const int row0 = bm + wr * 128 + mi * 16 + kq * 4;
        const f32x4 a = acc[mi][ni];
        const float bb = bp[colL];
        if (seg < 2) {
#pragma unroll
          for (int j = 0; j < 4; ++j)
            O[(size_t)(row0 + j) * 2048 + colL] = (_Float16)(a[j] + bb);
        } else {
          half4 h;
#pragma unroll
          for (int j = 0; j < 4; ++j) h[j] = (_Float16)(a[j] + bb);
          *(half4*)(O + (size_t)colL * 8192 + row0) = h;
        }
      }
    }
  } else {
#pragma unroll
    for (int mi = 0; mi < 8; ++mi) {
#pragma unroll
      for (int ni = 0; ni < 4; ++ni) {
        const int col  = bn + wc * 64 + ni * 16 + fr;
        const int row0 = bm + wr * 128 + mi * 16 + kq * 4;
        const f32x4 a = acc[mi][ni];
        if constexpr (MODE == 0) {
          float* O = (float*)out + (size_t)blockIdx.z * sO;
#pragma unroll
          for (int j = 0; j < 4; ++j) O[(size_t)(row0 + j) * ldo + col] = a[j];
        } else {  // MODE 3: fp16 row-major, no bias (scores)
          _Float16* O = (_Float16*)out + (size_t)blockIdx.z * sO;
#pragma unroll
          for (int j = 0; j < 4; ++j)
            O[(size_t)(row0 + j) * ldo + col] = (_Float16)a[j];
        }
      }
    }
  }
}

__device__ __forceinline__ float wave_max_f(float v) {
#pragma unroll
  for (int o = 32; o; o >>= 1) v = fmaxf(v, __shfl_xor(v, o));
  return v;
}
__device__ __forceinline__ float wave_sum_f(float v) {
#pragma unroll
  for (int o = 32; o; o >>= 1) v += __shfl_xor(v, o);
  return v;
}

// one 256-thread block per row of 4096 fp16 scores -> fp16 probabilities
__global__ __launch_bounds__(256) void softmax_rows(
    const _Float16* __restrict__ S, _Float16* __restrict__ P)
{
  __shared__ float rmax[4], rsum[4];
  const int tid = threadIdx.x;
  const _Float16* s = S + (size_t)blockIdx.x * 4096;
  _Float16*       p = P + (size_t)blockIdx.x * 4096;

  const half8 v0 = ((const half8*)s)[tid];
  const half8 v1 = ((const half8*)s)[tid + 256];
  float f[16];
#pragma unroll
  for (int j = 0; j < 8; ++j) { f[j] = (float)v0[j]; f[8 + j] = (float)v1[j]; }

  float m = f[0];
#pragma unroll
  for (int j = 1; j < 16; ++j) m = fmaxf(m, f[j]);
  m = wave_max_f(m);
  if ((tid & 63) == 0) rmax[tid >> 6] = m;
  __syncthreads();
  m = fmaxf(fmaxf(rmax[0], rmax[1]), fmaxf(rmax[2], rmax[3]));

  float sum = 0.f;
#pragma unroll
  for (int j = 0; j < 16; ++j) { f[j] = __expf(f[j] - m); sum += f[j]; }
  sum = wave_sum_f(sum);
  if ((tid & 63) == 0) rsum[tid >> 6] = sum;
  __syncthreads();
  sum = rsum[0] + rsum[1] + rsum[2] + rsum[3];
  const float inv = 1.0f / sum;

  half8 o0, o1;
#pragma unroll
  for (int j = 0; j < 8; ++j) {
    o0[j] = (_Float16)(f[j] * inv);
    o1[j] = (_Float16)(f[8 + j] * inv);
  }
  ((half8*)p)[tid] = o0;
  ((half8*)p)[tid + 256] = o1;
}

// fused fp32->fp16 cvt: dst is contiguous Xh|Wqh|Wkh|Wvh
__global__ __launch_bounds__(256) void cvt_all(
    const float* __restrict__ X,  const float* __restrict__ Wq,
    const float* __restrict__ Wk, const float* __restrict__ Wv,
    _Float16* __restrict__ dst, int nX4, int nW4)
{
  const int total = nX4 + 3 * nW4;
  const int stride = gridDim.x * 256;
  for (int idx = blockIdx.x * 256 + threadIdx.x; idx < total; idx += stride) {
    const float* src; int off;
    if (idx < nX4)                { src = X;  off = idx; }
    else if (idx < nX4 + nW4)     { src = Wq; off = idx - nX4; }
    else if (idx < nX4 + 2 * nW4) { src = Wk; off = idx - nX4 - nW4; }
    else                          { src = Wv; off = idx - nX4 - 2 * nW4; }
    const f32x4 x = ((const f32x4*)src)[off];
    half4 h;
#pragma unroll
    for (int j = 0; j < 4; ++j) h[j] = (_Float16)x[j];
    ((half4*)dst)[idx] = h;
  }
}

extern "C" void kernel_launch(void* const* d_in, const int* in_sizes, int n_in,
                              void* d_out, int out_size, void* d_ws, size_t ws_size,
                              hipStream_t stream)
{
  const float* X  = (const float*)d_in[0];
  const float* Wq = (const float*)d_in[1];
  const float* bq = (const float*)d_in[2];
  const float* Wk = (const float*)d_in[3];
  const float* bk = (const float*)d_in[4];
  const float* Wv = (const float*)d_in[5];
  const float* bv = (const float*)d_in[6];
  float* out = (float*)d_out;

  const size_t NX = (size_t)2 * 4096 * 2048;  // 16,777,216
  const size_t NW = (size_t)2048 * 2048;      //  4,194,304
  const size_t NS = (size_t)2 * 4096 * 4096;  // 33,554,432

  // Workspace layout (lifetime-aliased):
  //  [0 ..)         : Ssc fp16 (67MB) — earlier hosts Xh + Wq|Wk|Wv fp16
  //                   (contiguous concat = merged projection B matrix)
  //  [NS*4 ..)      : Q | Kp fp16 — later aliased by P fp16
  //  [NS*4+2*NX*2..): Vt fp16 [2048][8192]
  char* w = (char*)d_ws;
  _Float16* Ssc = (_Float16*)w;
  _Float16* Xh  = (_Float16*)w;
  _Float16* Wc  = (_Float16*)(w + NX * 2);            // [6144][2048] concat
  _Float16* Q   = (_Float16*)(w + NS * 4);
  _Float16* Kp  = (_Float16*)(w + NS * 4 + NX * 2);
  _Float16* P   = (_Float16*)(w + NS * 4);            // aliases Q+Kp
  _Float16* Vt  = (_Float16*)(w + NS * 4 + 2 * NX * 2);

  // 1) fused fp32 -> fp16 conversion (Xh|Wqh|Wkh|Wvh contiguous)
  cvt_all<<<2048, 256, 0, stream>>>(X, Wq, Wk, Wv, Xh,
                                    (int)(NX / 4), (int)(NW / 4));

  const dim3 blk(512);
  // 2) merged QKV projection: [8192,6144] = Xh @ Wc^T, segmented epilogue
  gemm256<1><<<dim3(32, 24, 1), blk, 0, stream>>>(
      Xh, 2048, Wc, 2048, bq, bk, bv, Q, Kp, Vt, 2048, 2048, 0, 0, 0);
  // 3) scores: per batch, S = Q K^T (fp16 out)
  gemm256<3><<<dim3(16, 16, 2), blk, 0, stream>>>(
      Q, 2048, Kp, 2048, nullptr, nullptr, nullptr, Ssc, nullptr, nullptr,
      4096, 2048, (size_t)4096 * 2048, (size_t)4096 * 2048,
      (size_t)4096 * 4096);
  // 4) row softmax (fp16 in) -> fp16 probs
  softmax_rows<<<8192, 256, 0, stream>>>(Ssc, P);
  // 5) out: per batch, [4096,2048] = P @ Vt^T
  gemm256<0><<<dim3(16, 8, 2), blk, 0, stream>>>(
      P, 4096, Vt, 8192, nullptr, nullptr, nullptr, out, nullptr, nullptr,
      2048, 4096, (size_t)4096 * 4096, (size_t)4096, (size_t)4096 * 2048);
}